// Round 9
// baseline (407.665 us; speedup 1.0000x reference)
//
#include <hip/hip_runtime.h>
#include <hip/hip_cooperative_groups.h>
#include <math.h>

namespace cg = cooperative_groups;

#define NB 8
#define CW 160
#define CPB (CW*CW)          // 25600 coarse pixels per batch
#define FW 640
#define PIX (FW*FW)          // 409600 full-res pixels per batch
#define MBLK 25              // coarse blocks per batch in main/val (4 px/thread)
#define PBLK 400             // pass1 units per batch (64 coarse px per unit)
#define HSUB 8               // hist sub-units per batch (3200 px each)
#define GRID 512             // cooperative grid (2 blocks/CU guaranteed)

// ---- workspace layout (bytes) ----
#define OFF_CNTS     0                          // u32[NB*CPB]
#define OFF_CI       (NB*CPB*4)                 // u64[NB*CPB]
#define OFF_CKC     (OFF_CI + NB*CPB*8)         // u64[NB*CPB]
#define OFF_PARTM   (OFF_CKC + NB*CPB*8)        // float[NB*MBLK*54]
#define OFF_PARTV   (OFF_PARTM + NB*MBLK*54*4)  // float[NB*MBLK*8]
#define OFF_POSNUM  (OFF_PARTV + NB*MBLK*8*4)   // int[NB]
#define OFF_HIST0   (OFF_POSNUM + NB*4)         // int[NB*2048]
#define OFF_HIST1   (OFF_HIST0 + NB*2048*4)     // int[NB*2048]
#define OFF_META    (OFF_HIST1 + NB*2048*4)     // int[NB*4]: d0, j1, fb
#define WS_END      (OFF_META + NB*16)

__device__ __forceinline__ float wredf(float v) {
    #pragma unroll
    for (int o = 32; o; o >>= 1) v += __shfl_xor(v, o, 64);
    return v;
}
__device__ __forceinline__ int wredi(int v) {
    #pragma unroll
    for (int o = 32; o; o >>= 1) v += __shfl_xor(v, o, 64);
    return v;
}
__device__ __forceinline__ unsigned long long wredu64(unsigned long long v) {
    #pragma unroll
    for (int o = 32; o; o >>= 1) v += __shfl_xor(v, o, 64);
    return v;
}
__device__ __forceinline__ unsigned keyxf(float f) {
    unsigned bits = __float_as_uint(f);
    return (bits & 0x80000000u) ? ~bits : (bits | 0x80000000u);
}

__device__ int coscan256(const int* __restrict__ hist, int nbins, int tid, int* s_sum) {
    int chunk = nbins >> 8;
    int base = tid * chunk;
    int s = 0;
    #pragma unroll 8
    for (int i = 0; i < chunk; i++) s += hist[base + i];
    s_sum[tid] = s;
    __syncthreads();
    #pragma unroll
    for (int off = 1; off < 256; off <<= 1) {
        int add = (tid >= off) ? s_sum[tid - off] : 0;
        __syncthreads();
        s_sum[tid] += add;
        __syncthreads();
    }
    return s_sum[255];
}
__device__ void cofind256(const int* __restrict__ hist, int nbins, int tid,
                          const int* s_sum, int j, int* s_out) {
    int chunk = nbins >> 8;
    if (tid == 0) { s_out[0] = 0; s_out[1] = 0; }
    __syncthreads();
    int incl = s_sum[tid];
    int excl = (tid > 0) ? s_sum[tid - 1] : 0;
    if (j >= excl && j < incl) {
        int base = tid * chunk, cum = excl;
        for (int i = 0; i < chunk; i++) {
            int c = hist[base + i];
            if (j < cum + c) { s_out[0] = base + i; s_out[1] = j - cum; break; }
            cum += c;
        }
    }
    __syncthreads();
}
__device__ __forceinline__ int ohem_j(int pn, int N) {
    long long nn = min(3LL * (long long)pn, (long long)N);
    int j = (int)((long long)N - nn);
    if (j < 0) j = 0;
    if (j >= N) j = (N > 0) ? N - 1 : 0;
    return j;
}

// =================== THE FUSED COOPERATIVE KERNEL ===================
__global__ __launch_bounds__(256, 2) void k_fused(const float* __restrict__ gt_texts,
                                                  const float* __restrict__ gt_kernels,
                                                  const int*   __restrict__ gt_instance,
                                                  const float* __restrict__ tm,
                                                  const float* __restrict__ maps,
                                                  unsigned* __restrict__ cnts,
                                                  unsigned long long* __restrict__ ciA,
                                                  unsigned long long* __restrict__ ckA,
                                                  int* __restrict__ posNum,
                                                  int* __restrict__ hist0,
                                                  int* __restrict__ hist1,
                                                  int* __restrict__ thrMeta,
                                                  float* __restrict__ partM,
                                                  float* __restrict__ partV,
                                                  float* __restrict__ out) {
    cg::grid_group grid = cg::this_grid();
    const int tid = threadIdx.x;
    const int nbk = gridDim.x;

    __shared__ int h[2048];
    __shared__ int s_sum[256];
    __shared__ int s_out[2];
    __shared__ unsigned long long s_ci[256];
    __shared__ unsigned long long s_ck[256];
    __shared__ unsigned s_cnt[256];

    // ---- zero hist0/hist1/posNum ----
    for (int i = blockIdx.x * 256 + tid; i < NB * 2048; i += nbk * 256) {
        hist0[i] = 0;
        hist1[i] = 0;
    }
    if (blockIdx.x == 0 && tid < NB) posNum[tid] = 0;

    // ================= Phase A: full-res streaming pass =================
    for (int u = blockIdx.x; u < NB * PBLK; u += nbk) {
        int b = u / PBLK;
        int blk = u - b * PBLK;
        int r = tid >> 6;
        int c = tid & 63;
        int cp = blk * 64 + c;
        int cy = cp / CW, cx = cp - cy * CW;
        size_t fbase = (size_t)b * PIX + (size_t)(cy * 4 + r) * FW + cx * 4;

        float4 g  = *reinterpret_cast<const float4*>(gt_texts   + fbase);
        float4 gk = *reinterpret_cast<const float4*>(gt_kernels + fbase);
        float4 m  = *reinterpret_cast<const float4*>(tm         + fbase);
        int4  idv = *reinterpret_cast<const int4*>(gt_instance + fbase);

        int neg = 0, c_tmb = 0, c_gt = 0, c_kb = 0;
        unsigned long long ci = 0, ck = 0;
        auto px = [&](float gg, float gkk, float mm, int id) {
            bool tmb = mm > 0.5f;
            bool gt  = gg > 0.5f;
            bool gkb = gkk > 0.5f;
            neg += !gt;
            c_tmb += tmb;
            c_gt += (gt && tmb);
            bool kb = tmb && gkb;
            c_kb += kb;
            ci += 1ull << ((tmb ? id : 0) * 8);
            ck += 1ull << ((kb ? id : 0) * 8);
        };
        px(g.x, gk.x, m.x, idv.x);
        px(g.y, gk.y, m.y, idv.y);
        px(g.z, gk.z, m.z, idv.z);
        px(g.w, gk.w, m.w, idv.w);

        s_ci[tid] = ci;
        s_ck[tid] = ck;
        s_cnt[tid] = (unsigned)c_tmb | ((unsigned)c_gt << 8) | ((unsigned)c_kb << 16) | ((unsigned)neg << 24);
        __syncthreads();
        if (tid < 64) {
            unsigned cs = s_cnt[tid] + s_cnt[tid + 64] + s_cnt[tid + 128] + s_cnt[tid + 192];
            unsigned long long cis = s_ci[tid] + s_ci[tid + 64] + s_ci[tid + 128] + s_ci[tid + 192];
            unsigned long long cks = s_ck[tid] + s_ck[tid + 64] + s_ck[tid + 128] + s_ck[tid + 192];
            int gidx = b * CPB + blk * 64 + tid;
            cnts[gidx] = cs;
            ciA[gidx] = cis;
            ckA[gidx] = cks;
        }
        __syncthreads();
    }
    grid.sync();

    // ================= Phase B: level-0 histogram + posNum =================
    for (int u = blockIdx.x; u < NB * HSUB; u += nbk) {
        int b = u >> 3, hb = u & 7;
        const float* tex = maps + (size_t)b * 6 * CPB;
        const unsigned* cn = cnts + b * CPB;
        for (int i = tid; i < 2048; i += 256) h[i] = 0;
        __syncthreads();
        int posSum = 0;
        #pragma unroll
        for (int it = 0; it < 4; it++) {
            int q = it * 256 + tid;
            if (q < 800) {
                int i0 = hb * 3200 + q * 4;
                float4 t4 = *reinterpret_cast<const float4*>(tex + i0);
                uint4  c4 = *reinterpret_cast<const uint4*>(cn + i0);
                float tv[4] = {t4.x, t4.y, t4.z, t4.w};
                unsigned cv[4] = {c4.x, c4.y, c4.z, c4.w};
                #pragma unroll
                for (int j = 0; j < 4; j++) {
                    posSum += (int)((cv[j] >> 8) & 255);
                    int w = (int)(cv[j] >> 24);
                    if (w) atomicAdd(&h[keyxf(tv[j]) >> 21], w);
                }
            }
        }
        posSum = wredi(posSum);
        if ((tid & 63) == 0 && posSum) atomicAdd(&posNum[b], posSum);
        __syncthreads();
        for (int i = tid; i < 2048; i += 256) {
            int v = h[i];
            if (v) atomicAdd(&hist0[b * 2048 + i], v);
        }
        __syncthreads();
    }
    grid.sync();

    // ========== Phase C: select d0 (per unit), build level-1 histogram ==========
    for (int u = blockIdx.x; u < NB * HSUB; u += nbk) {
        int b = u >> 3, hb = u & 7;
        const int* h0 = hist0 + b * 2048;
        int N = coscan256(h0, 2048, tid, s_sum);
        int pn = posNum[b];
        long long nn = min(3LL * (long long)pn, (long long)N);
        int fb = (pn == 0 || nn == 0) ? 1 : 0;
        int j0 = ohem_j(pn, N);
        cofind256(h0, 2048, tid, s_sum, j0, s_out);
        int d0 = s_out[0], j1 = s_out[1];
        if (hb == 0 && tid == 0) {
            thrMeta[b * 4]     = d0;
            thrMeta[b * 4 + 1] = j1;
            thrMeta[b * 4 + 2] = fb;
        }
        for (int i = tid; i < 2048; i += 256) h[i] = 0;
        __syncthreads();
        const float* tex = maps + (size_t)b * 6 * CPB;
        const unsigned* cn = cnts + b * CPB;
        #pragma unroll
        for (int it = 0; it < 4; it++) {
            int q = it * 256 + tid;
            if (q < 800) {
                int i0 = hb * 3200 + q * 4;
                float4 t4 = *reinterpret_cast<const float4*>(tex + i0);
                uint4  c4 = *reinterpret_cast<const uint4*>(cn + i0);
                float tv[4] = {t4.x, t4.y, t4.z, t4.w};
                unsigned cv[4] = {c4.x, c4.y, c4.z, c4.w};
                #pragma unroll
                for (int j = 0; j < 4; j++) {
                    int w = (int)(cv[j] >> 24);
                    if (!w) continue;
                    unsigned key = keyxf(tv[j]);
                    if ((int)(key >> 21) == d0) atomicAdd(&h[(key >> 10) & 0x7FF], w);
                }
            }
        }
        __syncthreads();
        for (int i = tid; i < 2048; i += 256) {
            int v = h[i];
            if (v) atomicAdd(&hist1[b * 2048 + i], v);
        }
        __syncthreads();
    }
    grid.sync();

    // ================= Phase D: main reduction =================
    for (int u = blockIdx.x; u < NB * MBLK; u += nbk) {
        int b = u / MBLK;
        int blk = u - b * MBLK;
        int p0 = (blk * 256 + tid) * 4;
        const float* mb = maps + (size_t)b * 6 * CPB;

        float txa[4], kna[4], e0a[4], e1a[4], e2a[4], e3a[4];
        *reinterpret_cast<float4*>(txa) = *reinterpret_cast<const float4*>(mb + p0);
        *reinterpret_cast<float4*>(kna) = *reinterpret_cast<const float4*>(mb + CPB + p0);
        *reinterpret_cast<float4*>(e0a) = *reinterpret_cast<const float4*>(mb + 2 * CPB + p0);
        *reinterpret_cast<float4*>(e1a) = *reinterpret_cast<const float4*>(mb + 3 * CPB + p0);
        *reinterpret_cast<float4*>(e2a) = *reinterpret_cast<const float4*>(mb + 4 * CPB + p0);
        *reinterpret_cast<float4*>(e3a) = *reinterpret_cast<const float4*>(mb + 5 * CPB + p0);
        unsigned ca[4];
        *reinterpret_cast<uint4*>(ca) = *reinterpret_cast<const uint4*>(cnts + b * CPB + p0);
        unsigned long long cia[4], cka[4];
        *reinterpret_cast<ulonglong2*>(cia)     = *reinterpret_cast<const ulonglong2*>(ciA + b * CPB + p0);
        *reinterpret_cast<ulonglong2*>(cia + 2) = *reinterpret_cast<const ulonglong2*>(ciA + b * CPB + p0 + 2);
        *reinterpret_cast<ulonglong2*>(cka)     = *reinterpret_cast<const ulonglong2*>(ckA + b * CPB + p0);
        *reinterpret_cast<ulonglong2*>(cka + 2) = *reinterpret_cast<const ulonglong2*>(ckA + b * CPB + p0 + 2);

        int d0 = thrMeta[b * 4], j1 = thrMeta[b * 4 + 1], fb = thrMeta[b * 4 + 2];
        const int* h1 = hist1 + b * 2048;
        coscan256(h1, 2048, tid, s_sum);
        cofind256(h1, 2048, tid, s_sum, j1, s_out);
        int d1 = s_out[0];
        unsigned key = ((unsigned)d0 << 21) | ((unsigned)d1 << 10);
        unsigned tb = (key & 0x80000000u) ? (key & 0x7FFFFFFFu) : ~key;
        float thr = __uint_as_float(tb);

        float at = 0.f, bt = 0.f, ct = 0.f, ak = 0.f, bk = 0.f, ckd = 0.f;
        unsigned long long ciS = 0, ckS = 0;
        float se[4][8];
        #pragma unroll
        for (int d = 0; d < 4; d++)
            #pragma unroll
            for (int k = 0; k < 8; k++) se[d][k] = 0.f;

        #pragma unroll
        for (int j = 0; j < 4; j++) {
            float tx = txa[j], kn = kna[j];
            unsigned c = ca[j];
            float c_tmb = (float)(c & 255);
            float c_gt  = (float)((c >> 8) & 255);
            float c_kb  = (float)((c >> 16) & 255);
            float sig_t = 1.f / (1.f + expf(-tx));
            float sig_k = 1.f / (1.f + expf(-kn));
            bool sge = (tx >= thr);
            bool skp = (tx > 0.0f);
            float n_sel = fb ? c_tmb : (sge ? c_tmb : c_gt);
            float n_selk = skp ? c_tmb : 0.f;
            float n_selk_g = skp ? c_kb : 0.f;
            at += sig_t * c_gt;
            bt += sig_t * sig_t * n_sel;
            ct += c_gt;
            ak += sig_k * n_selk_g;
            bk += sig_k * sig_k * n_selk;
            ckd += n_selk_g;
            ciS += cia[j];
            unsigned long long ck = cka[j];
            ckS += ck;
            #pragma unroll
            for (int k = 1; k < 8; k++) {
                float fc = (float)((ck >> (8 * k)) & 255);
                se[0][k] += e0a[j] * fc;
                se[1][k] += e1a[j] * fc;
                se[2][k] += e2a[j] * fc;
                se[3][k] += e3a[j] * fc;
            }
        }

        at = wredf(at); bt = wredf(bt); ct = wredf(ct);
        ak = wredf(ak); bk = wredf(bk); ckd = wredf(ckd);
        const unsigned long long M = 0x00FF00FF00FF00FFull;
        unsigned long long ci0 = wredu64(ciS & M);
        unsigned long long ci1 = wredu64((ciS >> 8) & M);
        unsigned long long ck0 = wredu64(ckS & M);
        unsigned long long ck1 = wredu64((ckS >> 8) & M);
        #pragma unroll
        for (int d = 0; d < 4; d++)
            #pragma unroll
            for (int k = 1; k < 8; k++) se[d][k] = wredf(se[d][k]);

        float* shf = (float*)h;                 // reuse LDS: 4*54 floats
        int w = tid >> 6;
        if ((tid & 63) == 0) {
            float* sw = shf + w * 54;
            sw[0] = at; sw[1] = bt; sw[2] = ct;
            sw[3] = ak; sw[4] = bk; sw[5] = ckd;
            #pragma unroll
            for (int q = 0; q < 4; q++) {
                sw[6 + 2 * q]      = (float)((ck0 >> (16 * q)) & 0xFFFF);
                sw[6 + 2 * q + 1]  = (float)((ck1 >> (16 * q)) & 0xFFFF);
                sw[14 + 2 * q]     = (float)((ci0 >> (16 * q)) & 0xFFFF);
                sw[14 + 2 * q + 1] = (float)((ci1 >> (16 * q)) & 0xFFFF);
            }
            #pragma unroll
            for (int d = 0; d < 4; d++) {
                sw[22 + d * 8] = 0.f;
                #pragma unroll
                for (int k = 1; k < 8; k++) sw[22 + d * 8 + k] = se[d][k];
            }
        }
        __syncthreads();
        if (tid < 54)
            partM[(size_t)(b * MBLK + blk) * 54 + tid] =
                shf[tid] + shf[54 + tid] + shf[108 + tid] + shf[162 + tid];
        __syncthreads();
    }
    grid.sync();

    // ================= Phase E: per-label log-dist sums =================
    for (int u = blockIdx.x; u < NB * MBLK; u += nbk) {
        int b = u / MBLK;
        int blk = u - b * MBLK;
        int p0 = (blk * 256 + tid) * 4;
        const float* mb = maps + (size_t)b * 6 * CPB;

        float e0a[4], e1a[4], e2a[4], e3a[4];
        *reinterpret_cast<float4*>(e0a) = *reinterpret_cast<const float4*>(mb + 2 * CPB + p0);
        *reinterpret_cast<float4*>(e1a) = *reinterpret_cast<const float4*>(mb + 3 * CPB + p0);
        *reinterpret_cast<float4*>(e2a) = *reinterpret_cast<const float4*>(mb + 4 * CPB + p0);
        *reinterpret_cast<float4*>(e3a) = *reinterpret_cast<const float4*>(mb + 5 * CPB + p0);
        unsigned long long cia[4];
        *reinterpret_cast<ulonglong2*>(cia)     = *reinterpret_cast<const ulonglong2*>(ciA + b * CPB + p0);
        *reinterpret_cast<ulonglong2*>(cia + 2) = *reinterpret_cast<const ulonglong2*>(ciA + b * CPB + p0 + 2);

        float* A54 = (float*)h;                 // [54]
        float* shm = A54 + 64;                  // [32]
        float* shv = A54 + 96;                  // [8]
        float* shp = A54 + 112;                 // [4][8]
        if (tid < 54) {
            float s = 0.f;
            #pragma unroll 5
            for (int j = 0; j < MBLK; j++) s += partM[(size_t)(b * MBLK + j) * 54 + tid];
            A54[tid] = s;
        }
        __syncthreads();
        if (tid < 32) {
            int k = tid & 7;
            shm[tid] = (k == 0) ? 0.f : A54[22 + tid] / fmaxf(A54[6 + k], 1.f);
        }
        if (tid < 8) shv[tid] = (tid != 0 && A54[6 + tid] > 0.f) ? 1.f : 0.f;
        __syncthreads();

        float sv[8];
        #pragma unroll
        for (int k = 0; k < 8; k++) sv[k] = 0.f;
        #pragma unroll
        for (int j = 0; j < 4; j++) {
            unsigned long long ci = cia[j];
            #pragma unroll
            for (int k = 1; k < 8; k++) {
                int c = (int)((ci >> (8 * k)) & 255);
                if (c && shv[k] > 0.5f) {
                    float d0 = e0a[j] - shm[k], d1 = e1a[j] - shm[8 + k];
                    float d2 = e2a[j] - shm[16 + k], d3 = e3a[j] - shm[24 + k];
                    float sq = d0 * d0 + d1 * d1 + d2 * d2 + d3 * d3;
                    float dist = sqrtf(fmaxf(sq, 1e-12f));
                    float t = fmaxf(dist - 0.5f, 0.f);
                    sv[k] += logf(t * t + 1.f) * (float)c;
                }
            }
        }
        #pragma unroll
        for (int k = 1; k < 8; k++) sv[k] = wredf(sv[k]);
        int w = tid >> 6;
        if ((tid & 63) == 0) {
            shp[w * 8] = 0.f;
            #pragma unroll
            for (int k = 1; k < 8; k++) shp[w * 8 + k] = sv[k];
        }
        __syncthreads();
        if (tid < 8)
            partV[(size_t)(b * MBLK + blk) * 8 + tid] =
                shp[tid] + shp[8 + tid] + shp[16 + tid] + shp[24 + tid];
        __syncthreads();
    }
    grid.sync();

    // ================= Phase F: finalize (block 0) =================
    if (blockIdx.x == 0) {
        float* AM = (float*)h;                  // [NB][54] = 432 floats
        float* SV = AM + 440;                   // [NB][8]
        float* totB = SV + 64;                  // [NB]
        for (int i = tid; i < NB * 54; i += 256) {
            int b = i / 54, c = i - b * 54;
            float s = 0.f;
            for (int j = 0; j < MBLK; j++) s += partM[(size_t)(b * MBLK + j) * 54 + c];
            AM[b * 54 + c] = s;
        }
        if (tid < 64) {
            int b = tid >> 3, k = tid & 7;
            float s = 0.f;
            for (int j = 0; j < MBLK; j++) s += partV[(size_t)(b * MBLK + j) * 8 + k];
            SV[b * 8 + k] = s;
        }
        __syncthreads();
        if (tid < NB) {
            int b = tid;
            const float* A = AM + b * 54;
            float ltext = 1.f - 2.f * A[0] / (A[1] + A[2] + 0.002f);
            float lkern = 1.f - 2.f * A[3] / (A[4] + A[5] + 0.002f);
            float m[4][8];
            float valid[8];
            int nv = 0, ninst = 0;
            #pragma unroll
            for (int k = 0; k < 8; k++) {
                float c = A[6 + k];
                float inv = 1.f / fmaxf(c, 1.f);
                #pragma unroll
                for (int d = 0; d < 4; d++) m[d][k] = (k == 0) ? 0.f : A[22 + d * 8 + k] * inv;
                int pres = (c > 0.f);
                ninst += pres;
                int v = pres && (k != 0);
                nv += v;
                valid[k] = (float)v;
            }
            float s = 0.f;
            for (int i = 1; i < 8; i++) {
                if (valid[i] < 0.5f) continue;
                for (int j = 1; j < 8; j++) {
                    if (j == i || valid[j] < 0.5f) continue;
                    float sq = 0.f;
                    #pragma unroll
                    for (int d = 0; d < 4; d++) { float df = m[d][i] - m[d][j]; sq += df * df; }
                    float pd = sqrtf(sq > 0.f ? sq : 1.f);
                    float t = fmaxf(3.f - pd, 0.f);
                    s += logf(t * t + 1.f);
                }
            }
            float pairs = (float)(nv * nv - nv);
            float l_dis = (nv >= 2) ? s / fmaxf(pairs, 1.f) : 0.f;
            float s2 = 0.f;
            for (int k = 0; k < 8; k++) {
                if (A[6 + k] > 0.f) {
                    float n2 = 0.f;
                    #pragma unroll
                    for (int d = 0; d < 4; d++) n2 += m[d][k] * m[d][k];
                    s2 += logf(sqrtf(n2) + 1.f);
                }
            }
            float l_reg = s2 / fmaxf((float)ninst, 1.f) * 0.001f;
            float lagg = 0.f;
            #pragma unroll
            for (int k = 0; k < 8; k++)
                lagg += valid[k] * (SV[b * 8 + k] / fmaxf(A[14 + k], 1.f));
            lagg /= fmaxf((float)nv, 1.f);
            float le = (nv > 0) ? (lagg + l_dis + l_reg) : 0.f;
            totB[b] = ltext + 0.5f * lkern + 0.25f * le;
        }
        __syncthreads();
        if (tid == 0) {
            float t = 0.f;
            for (int b = 0; b < NB; b++) t += totB[b];
            out[0] = t / (float)NB;
        }
    }
}

// =================== FALLBACK: proven 6-kernel pipeline ===================
__global__ __launch_bounds__(256) void k_pass1(const float* __restrict__ gt_texts,
                                               const float* __restrict__ gt_kernels,
                                               const int*   __restrict__ gt_instance,
                                               const float* __restrict__ tm,
                                               unsigned* __restrict__ cnts,
                                               unsigned long long* __restrict__ ciA,
                                               unsigned long long* __restrict__ ckA,
                                               int* __restrict__ posNum,
                                               int* __restrict__ hist0,
                                               int* __restrict__ hist1) {
    int tid = threadIdx.x;
    if (blockIdx.x < 64) {
        int zi = blockIdx.x * 256 + tid;
        hist0[zi] = 0;
        hist1[zi] = 0;
        if (zi < NB) posNum[zi] = 0;
    }
    int b = blockIdx.x / PBLK;
    int blk = blockIdx.x - b * PBLK;
    int r = tid >> 6;
    int c = tid & 63;
    int cp = blk * 64 + c;
    int cy = cp / CW, cx = cp - cy * CW;
    size_t fbase = (size_t)b * PIX + (size_t)(cy * 4 + r) * FW + cx * 4;
    float4 g  = *reinterpret_cast<const float4*>(gt_texts   + fbase);
    float4 gk = *reinterpret_cast<const float4*>(gt_kernels + fbase);
    float4 m  = *reinterpret_cast<const float4*>(tm         + fbase);
    int4  idv = *reinterpret_cast<const int4*>(gt_instance + fbase);
    int neg = 0, c_tmb = 0, c_gt = 0, c_kb = 0;
    unsigned long long ci = 0, ck = 0;
    auto px = [&](float gg, float gkk, float mm, int id) {
        bool tmb = mm > 0.5f;
        bool gt  = gg > 0.5f;
        bool gkb = gkk > 0.5f;
        neg += !gt;
        c_tmb += tmb;
        c_gt += (gt && tmb);
        bool kb = tmb && gkb;
        c_kb += kb;
        ci += 1ull << ((tmb ? id : 0) * 8);
        ck += 1ull << ((kb ? id : 0) * 8);
    };
    px(g.x, gk.x, m.x, idv.x);
    px(g.y, gk.y, m.y, idv.y);
    px(g.z, gk.z, m.z, idv.z);
    px(g.w, gk.w, m.w, idv.w);
    __shared__ unsigned long long s_ci[256];
    __shared__ unsigned long long s_ck[256];
    __shared__ unsigned s_cnt[256];
    s_ci[tid] = ci;
    s_ck[tid] = ck;
    s_cnt[tid] = (unsigned)c_tmb | ((unsigned)c_gt << 8) | ((unsigned)c_kb << 16) | ((unsigned)neg << 24);
    __syncthreads();
    if (tid < 64) {
        unsigned cs = s_cnt[tid] + s_cnt[tid + 64] + s_cnt[tid + 128] + s_cnt[tid + 192];
        unsigned long long cis = s_ci[tid] + s_ci[tid + 64] + s_ci[tid + 128] + s_ci[tid + 192];
        unsigned long long cks = s_ck[tid] + s_ck[tid + 64] + s_ck[tid + 128] + s_ck[tid + 192];
        int gidx = b * CPB + blk * 64 + tid;
        cnts[gidx] = cs;
        ciA[gidx] = cis;
        ckA[gidx] = cks;
    }
}

__global__ __launch_bounds__(256) void k_hist0(const float* __restrict__ maps,
                                               const unsigned* __restrict__ cnts,
                                               int* __restrict__ posNum,
                                               int* __restrict__ hist0) {
    int b = blockIdx.x >> 3, hb = blockIdx.x & 7, tid = threadIdx.x;
    const float* tex = maps + (size_t)b * 6 * CPB;
    const unsigned* cn = cnts + b * CPB;
    __shared__ int h[2048];
    for (int i = tid; i < 2048; i += 256) h[i] = 0;
    __syncthreads();
    int posSum = 0;
    #pragma unroll
    for (int it = 0; it < 4; it++) {
        int q = it * 256 + tid;
        if (q < 800) {
            int i0 = hb * 3200 + q * 4;
            float4 t4 = *reinterpret_cast<const float4*>(tex + i0);
            uint4  c4 = *reinterpret_cast<const uint4*>(cn + i0);
            float tv[4] = {t4.x, t4.y, t4.z, t4.w};
            unsigned cv[4] = {c4.x, c4.y, c4.z, c4.w};
            #pragma unroll
            for (int j = 0; j < 4; j++) {
                posSum += (int)((cv[j] >> 8) & 255);
                int w = (int)(cv[j] >> 24);
                if (w) atomicAdd(&h[keyxf(tv[j]) >> 21], w);
            }
        }
    }
    posSum = wredi(posSum);
    if ((tid & 63) == 0 && posSum) atomicAdd(&posNum[b], posSum);
    __syncthreads();
    for (int i = tid; i < 2048; i += 256) {
        int v = h[i];
        if (v) atomicAdd(&hist0[b * 2048 + i], v);
    }
}

__global__ __launch_bounds__(256) void k_hist1(const float* __restrict__ maps,
                                               const unsigned* __restrict__ cnts,
                                               const int* __restrict__ posNum,
                                               const int* __restrict__ hist0,
                                               int* __restrict__ hist1,
                                               int* __restrict__ thrMeta) {
    int b = blockIdx.x >> 3, hb = blockIdx.x & 7, tid = threadIdx.x;
    __shared__ int s_sum[256], s_out[2];
    const int* h0 = hist0 + b * 2048;
    int N = coscan256(h0, 2048, tid, s_sum);
    int pn = posNum[b];
    long long nn = min(3LL * (long long)pn, (long long)N);
    int fb = (pn == 0 || nn == 0) ? 1 : 0;
    int j0 = ohem_j(pn, N);
    cofind256(h0, 2048, tid, s_sum, j0, s_out);
    int d0 = s_out[0], j1 = s_out[1];
    if (hb == 0 && tid == 0) {
        thrMeta[b * 4] = d0; thrMeta[b * 4 + 1] = j1; thrMeta[b * 4 + 2] = fb;
    }
    __shared__ int h[2048];
    for (int i = tid; i < 2048; i += 256) h[i] = 0;
    __syncthreads();
    const float* tex = maps + (size_t)b * 6 * CPB;
    const unsigned* cn = cnts + b * CPB;
    #pragma unroll
    for (int it = 0; it < 4; it++) {
        int q = it * 256 + tid;
        if (q < 800) {
            int i0 = hb * 3200 + q * 4;
            float4 t4 = *reinterpret_cast<const float4*>(tex + i0);
            uint4  c4 = *reinterpret_cast<const uint4*>(cn + i0);
            float tv[4] = {t4.x, t4.y, t4.z, t4.w};
            unsigned cv[4] = {c4.x, c4.y, c4.z, c4.w};
            #pragma unroll
            for (int j = 0; j < 4; j++) {
                int w = (int)(cv[j] >> 24);
                if (!w) continue;
                unsigned key = keyxf(tv[j]);
                if ((int)(key >> 21) == d0) atomicAdd(&h[(key >> 10) & 0x7FF], w);
            }
        }
    }
    __syncthreads();
    for (int i = tid; i < 2048; i += 256) {
        int v = h[i];
        if (v) atomicAdd(&hist1[b * 2048 + i], v);
    }
}

__global__ __launch_bounds__(256) void k_main_c(const float* __restrict__ maps,
                                                const unsigned* __restrict__ cnts,
                                                const unsigned long long* __restrict__ ciA,
                                                const unsigned long long* __restrict__ ckA,
                                                const int* __restrict__ thrMeta,
                                                const int* __restrict__ hist1,
                                                float* __restrict__ partM) {
    int b = blockIdx.x / MBLK;
    int blk = blockIdx.x - b * MBLK;
    int tid = threadIdx.x;
    int p0 = (blk * 256 + tid) * 4;
    const float* mb = maps + (size_t)b * 6 * CPB;
    float txa[4], kna[4], e0a[4], e1a[4], e2a[4], e3a[4];
    *reinterpret_cast<float4*>(txa) = *reinterpret_cast<const float4*>(mb + p0);
    *reinterpret_cast<float4*>(kna) = *reinterpret_cast<const float4*>(mb + CPB + p0);
    *reinterpret_cast<float4*>(e0a) = *reinterpret_cast<const float4*>(mb + 2 * CPB + p0);
    *reinterpret_cast<float4*>(e1a) = *reinterpret_cast<const float4*>(mb + 3 * CPB + p0);
    *reinterpret_cast<float4*>(e2a) = *reinterpret_cast<const float4*>(mb + 4 * CPB + p0);
    *reinterpret_cast<float4*>(e3a) = *reinterpret_cast<const float4*>(mb + 5 * CPB + p0);
    unsigned ca[4];
    *reinterpret_cast<uint4*>(ca) = *reinterpret_cast<const uint4*>(cnts + b * CPB + p0);
    unsigned long long cia[4], cka[4];
    *reinterpret_cast<ulonglong2*>(cia)     = *reinterpret_cast<const ulonglong2*>(ciA + b * CPB + p0);
    *reinterpret_cast<ulonglong2*>(cia + 2) = *reinterpret_cast<const ulonglong2*>(ciA + b * CPB + p0 + 2);
    *reinterpret_cast<ulonglong2*>(cka)     = *reinterpret_cast<const ulonglong2*>(ckA + b * CPB + p0);
    *reinterpret_cast<ulonglong2*>(cka + 2) = *reinterpret_cast<const ulonglong2*>(ckA + b * CPB + p0 + 2);
    __shared__ int s_sum[256], s_out[2];
    int d0 = thrMeta[b * 4], j1 = thrMeta[b * 4 + 1], fb = thrMeta[b * 4 + 2];
    const int* h1 = hist1 + b * 2048;
    coscan256(h1, 2048, tid, s_sum);
    cofind256(h1, 2048, tid, s_sum, j1, s_out);
    int d1 = s_out[0];
    unsigned key = ((unsigned)d0 << 21) | ((unsigned)d1 << 10);
    unsigned tb = (key & 0x80000000u) ? (key & 0x7FFFFFFFu) : ~key;
    float thr = __uint_as_float(tb);
    float at = 0.f, bt = 0.f, ct = 0.f, ak = 0.f, bk = 0.f, ckd = 0.f;
    unsigned long long ciS = 0, ckS = 0;
    float se[4][8];
    #pragma unroll
    for (int d = 0; d < 4; d++)
        #pragma unroll
        for (int k = 0; k < 8; k++) se[d][k] = 0.f;
    #pragma unroll
    for (int j = 0; j < 4; j++) {
        float tx = txa[j], kn = kna[j];
        unsigned c = ca[j];
        float c_tmb = (float)(c & 255);
        float c_gt  = (float)((c >> 8) & 255);
        float c_kb  = (float)((c >> 16) & 255);
        float sig_t = 1.f / (1.f + expf(-tx));
        float sig_k = 1.f / (1.f + expf(-kn));
        bool sge = (tx >= thr);
        bool skp = (tx > 0.0f);
        float n_sel = fb ? c_tmb : (sge ? c_tmb : c_gt);
        float n_selk = skp ? c_tmb : 0.f;
        float n_selk_g = skp ? c_kb : 0.f;
        at += sig_t * c_gt;
        bt += sig_t * sig_t * n_sel;
        ct += c_gt;
        ak += sig_k * n_selk_g;
        bk += sig_k * sig_k * n_selk;
        ckd += n_selk_g;
        ciS += cia[j];
        unsigned long long ck = cka[j];
        ckS += ck;
        #pragma unroll
        for (int k = 1; k < 8; k++) {
            float fc = (float)((ck >> (8 * k)) & 255);
            se[0][k] += e0a[j] * fc;
            se[1][k] += e1a[j] * fc;
            se[2][k] += e2a[j] * fc;
            se[3][k] += e3a[j] * fc;
        }
    }
    at = wredf(at); bt = wredf(bt); ct = wredf(ct);
    ak = wredf(ak); bk = wredf(bk); ckd = wredf(ckd);
    const unsigned long long M = 0x00FF00FF00FF00FFull;
    unsigned long long ci0 = wredu64(ciS & M);
    unsigned long long ci1 = wredu64((ciS >> 8) & M);
    unsigned long long ck0 = wredu64(ckS & M);
    unsigned long long ck1 = wredu64((ckS >> 8) & M);
    #pragma unroll
    for (int d = 0; d < 4; d++)
        #pragma unroll
        for (int k = 1; k < 8; k++) se[d][k] = wredf(se[d][k]);
    __shared__ float sh[4][54];
    int w = tid >> 6;
    if ((tid & 63) == 0) {
        sh[w][0] = at; sh[w][1] = bt; sh[w][2] = ct;
        sh[w][3] = ak; sh[w][4] = bk; sh[w][5] = ckd;
        #pragma unroll
        for (int q = 0; q < 4; q++) {
            sh[w][6 + 2 * q]      = (float)((ck0 >> (16 * q)) & 0xFFFF);
            sh[w][6 + 2 * q + 1]  = (float)((ck1 >> (16 * q)) & 0xFFFF);
            sh[w][14 + 2 * q]     = (float)((ci0 >> (16 * q)) & 0xFFFF);
            sh[w][14 + 2 * q + 1] = (float)((ci1 >> (16 * q)) & 0xFFFF);
        }
        #pragma unroll
        for (int d = 0; d < 4; d++) {
            sh[w][22 + d * 8] = 0.f;
            #pragma unroll
            for (int k = 1; k < 8; k++) sh[w][22 + d * 8 + k] = se[d][k];
        }
    }
    __syncthreads();
    if (tid < 54)
        partM[(size_t)(b * MBLK + blk) * 54 + tid] =
            sh[0][tid] + sh[1][tid] + sh[2][tid] + sh[3][tid];
}

__global__ __launch_bounds__(256) void k_val_c(const float* __restrict__ maps,
                                               const unsigned long long* __restrict__ ciA,
                                               const float* __restrict__ partM,
                                               float* __restrict__ partV) {
    int b = blockIdx.x / MBLK;
    int blk = blockIdx.x - b * MBLK;
    int tid = threadIdx.x;
    int p0 = (blk * 256 + tid) * 4;
    const float* mb = maps + (size_t)b * 6 * CPB;
    float e0a[4], e1a[4], e2a[4], e3a[4];
    *reinterpret_cast<float4*>(e0a) = *reinterpret_cast<const float4*>(mb + 2 * CPB + p0);
    *reinterpret_cast<float4*>(e1a) = *reinterpret_cast<const float4*>(mb + 3 * CPB + p0);
    *reinterpret_cast<float4*>(e2a) = *reinterpret_cast<const float4*>(mb + 4 * CPB + p0);
    *reinterpret_cast<float4*>(e3a) = *reinterpret_cast<const float4*>(mb + 5 * CPB + p0);
    unsigned long long cia[4];
    *reinterpret_cast<ulonglong2*>(cia)     = *reinterpret_cast<const ulonglong2*>(ciA + b * CPB + p0);
    *reinterpret_cast<ulonglong2*>(cia + 2) = *reinterpret_cast<const ulonglong2*>(ciA + b * CPB + p0 + 2);
    __shared__ float A54[54];
    __shared__ float shm[32];
    __shared__ float shv[8];
    if (tid < 54) {
        float s = 0.f;
        #pragma unroll 5
        for (int j = 0; j < MBLK; j++) s += partM[(size_t)(b * MBLK + j) * 54 + tid];
        A54[tid] = s;
    }
    __syncthreads();
    if (tid < 32) {
        int k = tid & 7;
        shm[tid] = (k == 0) ? 0.f : A54[22 + tid] / fmaxf(A54[6 + k], 1.f);
    }
    if (tid < 8) shv[tid] = (tid != 0 && A54[6 + tid] > 0.f) ? 1.f : 0.f;
    __syncthreads();
    float sv[8];
    #pragma unroll
    for (int k = 0; k < 8; k++) sv[k] = 0.f;
    #pragma unroll
    for (int j = 0; j < 4; j++) {
        unsigned long long ci = cia[j];
        #pragma unroll
        for (int k = 1; k < 8; k++) {
            int c = (int)((ci >> (8 * k)) & 255);
            if (c && shv[k] > 0.5f) {
                float d0 = e0a[j] - shm[k], d1 = e1a[j] - shm[8 + k];
                float d2 = e2a[j] - shm[16 + k], d3 = e3a[j] - shm[24 + k];
                float sq = d0 * d0 + d1 * d1 + d2 * d2 + d3 * d3;
                float dist = sqrtf(fmaxf(sq, 1e-12f));
                float t = fmaxf(dist - 0.5f, 0.f);
                sv[k] += logf(t * t + 1.f) * (float)c;
            }
        }
    }
    #pragma unroll
    for (int k = 1; k < 8; k++) sv[k] = wredf(sv[k]);
    __shared__ float shp[4][8];
    int w = tid >> 6;
    if ((tid & 63) == 0) {
        shp[w][0] = 0.f;
        #pragma unroll
        for (int k = 1; k < 8; k++) shp[w][k] = sv[k];
    }
    __syncthreads();
    if (tid < 8)
        partV[(size_t)(b * MBLK + blk) * 8 + tid] =
            shp[0][tid] + shp[1][tid] + shp[2][tid] + shp[3][tid];
}

__global__ __launch_bounds__(64) void k_final(const float* __restrict__ partM,
                                              const float* __restrict__ partV,
                                              float* __restrict__ out) {
    int tid = threadIdx.x;
    __shared__ float AM[NB][54];
    __shared__ float SV[NB][8];
    __shared__ float tot[NB];
    for (int i = tid; i < NB * 54; i += 64) {
        int b = i / 54, c = i - b * 54;
        float s = 0.f;
        for (int j = 0; j < MBLK; j++) s += partM[(size_t)(b * MBLK + j) * 54 + c];
        AM[b][c] = s;
    }
    {
        int b = tid >> 3, k = tid & 7;
        float s = 0.f;
        for (int j = 0; j < MBLK; j++) s += partV[(size_t)(b * MBLK + j) * 8 + k];
        SV[b][k] = s;
    }
    __syncthreads();
    if (tid < NB) {
        int b = tid;
        const float* A = AM[b];
        float ltext = 1.f - 2.f * A[0] / (A[1] + A[2] + 0.002f);
        float lkern = 1.f - 2.f * A[3] / (A[4] + A[5] + 0.002f);
        float m[4][8];
        float valid[8];
        int nv = 0, ninst = 0;
        #pragma unroll
        for (int k = 0; k < 8; k++) {
            float c = A[6 + k];
            float inv = 1.f / fmaxf(c, 1.f);
            #pragma unroll
            for (int d = 0; d < 4; d++) m[d][k] = (k == 0) ? 0.f : A[22 + d * 8 + k] * inv;
            int pres = (c > 0.f);
            ninst += pres;
            int v = pres && (k != 0);
            nv += v;
            valid[k] = (float)v;
        }
        float s = 0.f;
        for (int i = 1; i < 8; i++) {
            if (valid[i] < 0.5f) continue;
            for (int j = 1; j < 8; j++) {
                if (j == i || valid[j] < 0.5f) continue;
                float sq = 0.f;
                #pragma unroll
                for (int d = 0; d < 4; d++) { float df = m[d][i] - m[d][j]; sq += df * df; }
                float pd = sqrtf(sq > 0.f ? sq : 1.f);
                float t = fmaxf(3.f - pd, 0.f);
                s += logf(t * t + 1.f);
            }
        }
        float pairs = (float)(nv * nv - nv);
        float l_dis = (nv >= 2) ? s / fmaxf(pairs, 1.f) : 0.f;
        float s2 = 0.f;
        for (int k = 0; k < 8; k++) {
            if (A[6 + k] > 0.f) {
                float n2 = 0.f;
                #pragma unroll
                for (int d = 0; d < 4; d++) n2 += m[d][k] * m[d][k];
                s2 += logf(sqrtf(n2) + 1.f);
            }
        }
        float l_reg = s2 / fmaxf((float)ninst, 1.f) * 0.001f;
        float lagg = 0.f;
        #pragma unroll
        for (int k = 0; k < 8; k++)
            lagg += valid[k] * (SV[b][k] / fmaxf(A[14 + k], 1.f));
        lagg /= fmaxf((float)nv, 1.f);
        float le = (nv > 0) ? (lagg + l_dis + l_reg) : 0.f;
        tot[b] = ltext + 0.5f * lkern + 0.25f * le;
    }
    __syncthreads();
    if (tid == 0) {
        float t = 0.f;
        for (int b = 0; b < NB; b++) t += tot[b];
        out[0] = t / (float)NB;
    }
}

extern "C" void kernel_launch(void* const* d_in, const int* in_sizes, int n_in,
                              void* d_out, int out_size, void* d_ws, size_t ws_size,
                              hipStream_t stream) {
    const float* maps        = (const float*)d_in[0];
    const float* gt_texts    = (const float*)d_in[1];
    const float* gt_kernels  = (const float*)d_in[2];
    const int*   gt_instance = (const int*)d_in[3];
    const float* tm          = (const float*)d_in[4];
    char* ws = (char*)d_ws;
    unsigned* cnts  = (unsigned*)(ws + OFF_CNTS);
    unsigned long long* ciA = (unsigned long long*)(ws + OFF_CI);
    unsigned long long* ckA = (unsigned long long*)(ws + OFF_CKC);
    float* partM    = (float*)(ws + OFF_PARTM);
    float* partV    = (float*)(ws + OFF_PARTV);
    int*   posNum   = (int*)(ws + OFF_POSNUM);
    int*   hist0    = (int*)(ws + OFF_HIST0);
    int*   hist1    = (int*)(ws + OFF_HIST1);
    int*   thrMeta  = (int*)(ws + OFF_META);
    float* outp     = (float*)d_out;

    void* args[] = { &gt_texts, &gt_kernels, &gt_instance, &tm, &maps,
                     &cnts, &ciA, &ckA, &posNum, &hist0, &hist1, &thrMeta,
                     &partM, &partV, &outp };
    hipError_t err = hipLaunchCooperativeKernel((const void*)k_fused,
                                                dim3(GRID), dim3(256),
                                                args, 0, stream);
    if (err != hipSuccess) {
        // deterministic fallback: proven multi-kernel pipeline
        k_pass1<<<NB * PBLK, 256, 0, stream>>>(gt_texts, gt_kernels, gt_instance, tm,
                                               cnts, ciA, ckA, posNum, hist0, hist1);
        k_hist0<<<NB * HSUB, 256, 0, stream>>>(maps, cnts, posNum, hist0);
        k_hist1<<<NB * HSUB, 256, 0, stream>>>(maps, cnts, posNum, hist0, hist1, thrMeta);
        k_main_c<<<NB * MBLK, 256, 0, stream>>>(maps, cnts, ciA, ckA, thrMeta, hist1, partM);
        k_val_c<<<NB * MBLK, 256, 0, stream>>>(maps, ciA, partM, partV);
        k_final<<<1, 64, 0, stream>>>(partM, partV, (float*)d_out);
    }
}

// Round 10
// 137.986 us; speedup vs baseline: 2.9544x; 2.9544x over previous
//
#include <hip/hip_runtime.h>
#include <math.h>

#define NB 8
#define CW 160
#define CPB (CW*CW)          // 25600 coarse pixels per batch
#define FW 640
#define PIX (FW*FW)          // 409600 full-res pixels per batch
#define MBLK 25              // coarse blocks per batch in k_main_c/k_val_c (4 px/thread)
#define PBLK 400             // pass1 blocks per batch (64 coarse px per block)
#define HSUB 8               // hist sub-blocks per batch (3200 px each)

// ---- workspace layout (bytes) ----
#define OFF_CNTS     0                          // u32[NB*CPB]: cnt_tmb | cnt_gt_tmb<<8 | cnt_kb_tmb<<16 | neg<<24
#define OFF_CI       (NB*CPB*4)                 // u64[NB*CPB]
#define OFF_CKC     (OFF_CI + NB*CPB*8)         // u64[NB*CPB]
#define OFF_PARTM   (OFF_CKC + NB*CPB*8)        // float[NB*MBLK*54]
#define OFF_PARTV   (OFF_PARTM + NB*MBLK*54*4)  // float[NB*MBLK*8]
#define OFF_POSNUM  (OFF_PARTV + NB*MBLK*8*4)   // int[NB]
#define OFF_HIST0   (OFF_POSNUM + NB*4)         // int[NB*2048]
#define OFF_HIST1   (OFF_HIST0 + NB*2048*4)     // int[NB*2048]
#define WS_END      (OFF_HIST1 + NB*2048*4)

__device__ __forceinline__ float wredf(float v) {
    #pragma unroll
    for (int o = 32; o; o >>= 1) v += __shfl_xor(v, o, 64);
    return v;
}
__device__ __forceinline__ int wredi(int v) {
    #pragma unroll
    for (int o = 32; o; o >>= 1) v += __shfl_xor(v, o, 64);
    return v;
}
__device__ __forceinline__ unsigned long long wredu64(unsigned long long v) {
    #pragma unroll
    for (int o = 32; o; o >>= 1) v += __shfl_xor(v, o, 64);
    return v;
}
__device__ __forceinline__ unsigned keyxf(float f) {
    unsigned bits = __float_as_uint(f);
    return (bits & 0x80000000u) ? ~bits : (bits | 0x80000000u);
}

// ---- 256-thread cooperative select helpers (hist may be global or LDS) ----
__device__ int coscan256(const int* __restrict__ hist, int nbins, int tid, int* s_sum) {
    int chunk = nbins >> 8;
    int base = tid * chunk;
    int s = 0;
    #pragma unroll 8
    for (int i = 0; i < chunk; i++) s += hist[base + i];
    s_sum[tid] = s;
    __syncthreads();
    #pragma unroll
    for (int off = 1; off < 256; off <<= 1) {
        int add = (tid >= off) ? s_sum[tid - off] : 0;
        __syncthreads();
        s_sum[tid] += add;
        __syncthreads();
    }
    return s_sum[255];
}
__device__ void cofind256(const int* __restrict__ hist, int nbins, int tid,
                          const int* s_sum, int j, int* s_out) {
    int chunk = nbins >> 8;
    if (tid == 0) { s_out[0] = 0; s_out[1] = 0; }
    __syncthreads();
    int incl = s_sum[tid];
    int excl = (tid > 0) ? s_sum[tid - 1] : 0;
    if (j >= excl && j < incl) {
        int base = tid * chunk, cum = excl;
        for (int i = 0; i < chunk; i++) {
            int c = hist[base + i];
            if (j < cum + c) { s_out[0] = base + i; s_out[1] = j - cum; break; }
            cum += c;
        }
    }
    __syncthreads();
}
__device__ __forceinline__ int ohem_j(int pn, int N) {
    long long nn = min(3LL * (long long)pn, (long long)N);
    int j = (int)((long long)N - nn);
    if (j < 0) j = 0;
    if (j >= N) j = (N > 0) ? N - 1 : 0;
    return j;
}

// ---------------- Kernel 1: full-res pass (high-TLP) + zero-init of hist/posNum ----------------
__global__ __launch_bounds__(256) void k_pass1(const float* __restrict__ gt_texts,
                                               const float* __restrict__ gt_kernels,
                                               const int*   __restrict__ gt_instance,
                                               const float* __restrict__ tm,
                                               unsigned* __restrict__ cnts,
                                               unsigned long long* __restrict__ ciA,
                                               unsigned long long* __restrict__ ckA,
                                               int* __restrict__ posNum,
                                               int* __restrict__ hist0,
                                               int* __restrict__ hist1) {
    int tid = threadIdx.x;
    // zero hist0/hist1/posNum (consumed only by later dispatches)
    if (blockIdx.x < 64) {
        int zi = blockIdx.x * 256 + tid;      // 0..16383 == NB*2048
        hist0[zi] = 0;
        hist1[zi] = 0;
        if (zi < NB) posNum[zi] = 0;
    }
    int b = blockIdx.x / PBLK;
    int blk = blockIdx.x - b * PBLK;          // 0..399
    int r = tid >> 6;                         // row within 4x4 block = wave id
    int c = tid & 63;                         // coarse px within block's 64
    int cp = blk * 64 + c;
    int cy = cp / CW, cx = cp - cy * CW;
    size_t fbase = (size_t)b * PIX + (size_t)(cy * 4 + r) * FW + cx * 4;

    float4 g  = *reinterpret_cast<const float4*>(gt_texts   + fbase);
    float4 gk = *reinterpret_cast<const float4*>(gt_kernels + fbase);
    float4 m  = *reinterpret_cast<const float4*>(tm         + fbase);
    int4  idv = *reinterpret_cast<const int4*>(gt_instance + fbase);

    int neg = 0, c_tmb = 0, c_gt = 0, c_kb = 0;
    unsigned long long ci = 0, ck = 0;
    auto px = [&](float gg, float gkk, float mm, int id) {
        bool tmb = mm > 0.5f;
        bool gt  = gg > 0.5f;
        bool gkb = gkk > 0.5f;
        neg += !gt;
        c_tmb += tmb;
        c_gt += (gt && tmb);
        bool kb = tmb && gkb;
        c_kb += kb;
        ci += 1ull << ((tmb ? id : 0) * 8);
        ck += 1ull << ((kb ? id : 0) * 8);
    };
    px(g.x, gk.x, m.x, idv.x);
    px(g.y, gk.y, m.y, idv.y);
    px(g.z, gk.z, m.z, idv.z);
    px(g.w, gk.w, m.w, idv.w);

    __shared__ unsigned long long s_ci[256];
    __shared__ unsigned long long s_ck[256];
    __shared__ unsigned s_cnt[256];
    s_ci[tid] = ci;
    s_ck[tid] = ck;
    s_cnt[tid] = (unsigned)c_tmb | ((unsigned)c_gt << 8) | ((unsigned)c_kb << 16) | ((unsigned)neg << 24);
    __syncthreads();
    if (tid < 64) {
        unsigned cs = s_cnt[tid] + s_cnt[tid + 64] + s_cnt[tid + 128] + s_cnt[tid + 192];
        unsigned long long cis = s_ci[tid] + s_ci[tid + 64] + s_ci[tid + 128] + s_ci[tid + 192];
        unsigned long long cks = s_ck[tid] + s_ck[tid + 64] + s_ck[tid + 128] + s_ck[tid + 192];
        int gidx = b * CPB + blk * 64 + tid;
        cnts[gidx] = cs;
        ciA[gidx] = cis;
        ckA[gidx] = cks;
    }
}

// ---------------- Kernel 2: level-0 histogram (top-11 key bits), 8 blocks/batch ----------------
__global__ __launch_bounds__(256) void k_hist0(const float* __restrict__ maps,
                                               const unsigned* __restrict__ cnts,
                                               int* __restrict__ posNum,
                                               int* __restrict__ hist0) {
    int b = blockIdx.x >> 3, hb = blockIdx.x & 7, tid = threadIdx.x;
    const float* tex = maps + (size_t)b * 6 * CPB;
    const unsigned* cn = cnts + b * CPB;
    __shared__ int h[2048];
    for (int i = tid; i < 2048; i += 256) h[i] = 0;
    __syncthreads();
    int posSum = 0;
    #pragma unroll
    for (int it = 0; it < 4; it++) {
        int q = it * 256 + tid;
        if (q < 800) {
            int i0 = hb * 3200 + q * 4;
            float4 t4 = *reinterpret_cast<const float4*>(tex + i0);
            uint4  c4 = *reinterpret_cast<const uint4*>(cn + i0);
            float tv[4] = {t4.x, t4.y, t4.z, t4.w};
            unsigned cv[4] = {c4.x, c4.y, c4.z, c4.w};
            #pragma unroll
            for (int j = 0; j < 4; j++) {
                posSum += (int)((cv[j] >> 8) & 255);
                int w = (int)(cv[j] >> 24);
                if (w) atomicAdd(&h[keyxf(tv[j]) >> 21], w);
            }
        }
    }
    posSum = wredi(posSum);
    if ((tid & 63) == 0 && posSum) atomicAdd(&posNum[b], posSum);
    __syncthreads();
    for (int i = tid; i < 2048; i += 256) {
        int v = h[i];
        if (v) atomicAdd(&hist0[b * 2048 + i], v);
    }
}

// ---------------- Kernel 3: select d0 (redundant per block), level-1 histogram ----------------
__global__ __launch_bounds__(256) void k_hist1(const float* __restrict__ maps,
                                               const unsigned* __restrict__ cnts,
                                               const int* __restrict__ posNum,
                                               const int* __restrict__ hist0,
                                               int* __restrict__ hist1) {
    int b = blockIdx.x >> 3, hb = blockIdx.x & 7, tid = threadIdx.x;
    __shared__ int s_sum[256], s_out[2];
    const int* h0 = hist0 + b * 2048;
    int N = coscan256(h0, 2048, tid, s_sum);
    int j0 = ohem_j(posNum[b], N);
    cofind256(h0, 2048, tid, s_sum, j0, s_out);
    int d0 = s_out[0];
    __shared__ int h[2048];
    for (int i = tid; i < 2048; i += 256) h[i] = 0;
    __syncthreads();
    const float* tex = maps + (size_t)b * 6 * CPB;
    const unsigned* cn = cnts + b * CPB;
    #pragma unroll
    for (int it = 0; it < 4; it++) {
        int q = it * 256 + tid;
        if (q < 800) {
            int i0 = hb * 3200 + q * 4;
            float4 t4 = *reinterpret_cast<const float4*>(tex + i0);
            uint4  c4 = *reinterpret_cast<const uint4*>(cn + i0);
            float tv[4] = {t4.x, t4.y, t4.z, t4.w};
            unsigned cv[4] = {c4.x, c4.y, c4.z, c4.w};
            #pragma unroll
            for (int j = 0; j < 4; j++) {
                int w = (int)(cv[j] >> 24);
                if (!w) continue;
                unsigned key = keyxf(tv[j]);
                if ((int)(key >> 21) == d0) atomicAdd(&h[(key >> 10) & 0x7FF], w);
            }
        }
    }
    __syncthreads();
    for (int i = tid; i < 2048; i += 256) {
        int v = h[i];
        if (v) atomicAdd(&hist1[b * 2048 + i], v);
    }
}

// ---------------- Kernel 4: main reduction; per-block 2-level select from global hists ----------------
// Threshold = lower edge of the selected 22-bit bucket (exact to 2^-14 relative;
// superset selection, loss delta ~1e-5 << 2.8e-2 tolerance).
__global__ __launch_bounds__(256) void k_main_c(const float* __restrict__ maps,
                                                const unsigned* __restrict__ cnts,
                                                const unsigned long long* __restrict__ ciA,
                                                const unsigned long long* __restrict__ ckA,
                                                const int* __restrict__ posNum,
                                                const int* __restrict__ hist0,
                                                const int* __restrict__ hist1,
                                                float* __restrict__ partM) {
    int b = blockIdx.x / MBLK;
    int blk = blockIdx.x - b * MBLK;
    int tid = threadIdx.x;
    int p0 = (blk * 256 + tid) * 4;
    const float* mb = maps + (size_t)b * 6 * CPB;

    // issue data loads first; select preamble overlaps their latency
    float txa[4], kna[4], e0a[4], e1a[4], e2a[4], e3a[4];
    *reinterpret_cast<float4*>(txa) = *reinterpret_cast<const float4*>(mb + p0);
    *reinterpret_cast<float4*>(kna) = *reinterpret_cast<const float4*>(mb + CPB + p0);
    *reinterpret_cast<float4*>(e0a) = *reinterpret_cast<const float4*>(mb + 2 * CPB + p0);
    *reinterpret_cast<float4*>(e1a) = *reinterpret_cast<const float4*>(mb + 3 * CPB + p0);
    *reinterpret_cast<float4*>(e2a) = *reinterpret_cast<const float4*>(mb + 4 * CPB + p0);
    *reinterpret_cast<float4*>(e3a) = *reinterpret_cast<const float4*>(mb + 5 * CPB + p0);
    unsigned ca[4];
    *reinterpret_cast<uint4*>(ca) = *reinterpret_cast<const uint4*>(cnts + b * CPB + p0);
    unsigned long long cia[4], cka[4];
    *reinterpret_cast<ulonglong2*>(cia)     = *reinterpret_cast<const ulonglong2*>(ciA + b * CPB + p0);
    *reinterpret_cast<ulonglong2*>(cia + 2) = *reinterpret_cast<const ulonglong2*>(ciA + b * CPB + p0 + 2);
    *reinterpret_cast<ulonglong2*>(cka)     = *reinterpret_cast<const ulonglong2*>(ckA + b * CPB + p0);
    *reinterpret_cast<ulonglong2*>(cka + 2) = *reinterpret_cast<const ulonglong2*>(ckA + b * CPB + p0 + 2);

    __shared__ int s_sum[256], s_out[2];
    const int* h0 = hist0 + b * 2048;
    const int* h1 = hist1 + b * 2048;
    int N = coscan256(h0, 2048, tid, s_sum);
    int pn = posNum[b];
    long long nn = min(3LL * (long long)pn, (long long)N);
    int fb = (pn == 0 || nn == 0) ? 1 : 0;
    int j0 = ohem_j(pn, N);
    cofind256(h0, 2048, tid, s_sum, j0, s_out);
    int d0 = s_out[0], j1 = s_out[1];
    coscan256(h1, 2048, tid, s_sum);
    cofind256(h1, 2048, tid, s_sum, j1, s_out);
    int d1 = s_out[0];
    unsigned key = ((unsigned)d0 << 21) | ((unsigned)d1 << 10);
    unsigned tb = (key & 0x80000000u) ? (key & 0x7FFFFFFFu) : ~key;
    float thr = __uint_as_float(tb);

    float at = 0.f, bt = 0.f, ct = 0.f, ak = 0.f, bk = 0.f, ckd = 0.f;
    unsigned long long ciS = 0, ckS = 0;
    float se[4][8];
    #pragma unroll
    for (int d = 0; d < 4; d++)
        #pragma unroll
        for (int k = 0; k < 8; k++) se[d][k] = 0.f;

    #pragma unroll
    for (int j = 0; j < 4; j++) {
        float tx = txa[j], kn = kna[j];
        unsigned c = ca[j];
        float c_tmb = (float)(c & 255);
        float c_gt  = (float)((c >> 8) & 255);
        float c_kb  = (float)((c >> 16) & 255);
        float sig_t = 1.f / (1.f + expf(-tx));
        float sig_k = 1.f / (1.f + expf(-kn));
        bool sge = (tx >= thr);
        bool skp = (tx > 0.0f);
        float n_sel = fb ? c_tmb : (sge ? c_tmb : c_gt);
        float n_selk = skp ? c_tmb : 0.f;
        float n_selk_g = skp ? c_kb : 0.f;
        at += sig_t * c_gt;
        bt += sig_t * sig_t * n_sel;
        ct += c_gt;
        ak += sig_k * n_selk_g;
        bk += sig_k * sig_k * n_selk;
        ckd += n_selk_g;
        ciS += cia[j];
        unsigned long long ck = cka[j];
        ckS += ck;
        #pragma unroll
        for (int k = 1; k < 8; k++) {
            float fc = (float)((ck >> (8 * k)) & 255);
            se[0][k] += e0a[j] * fc;
            se[1][k] += e1a[j] * fc;
            se[2][k] += e2a[j] * fc;
            se[3][k] += e3a[j] * fc;
        }
    }

    at = wredf(at); bt = wredf(bt); ct = wredf(ct);
    ak = wredf(ak); bk = wredf(bk); ckd = wredf(ckd);
    const unsigned long long M = 0x00FF00FF00FF00FFull;
    unsigned long long ci0 = wredu64(ciS & M);
    unsigned long long ci1 = wredu64((ciS >> 8) & M);
    unsigned long long ck0 = wredu64(ckS & M);
    unsigned long long ck1 = wredu64((ckS >> 8) & M);
    #pragma unroll
    for (int d = 0; d < 4; d++)
        #pragma unroll
        for (int k = 1; k < 8; k++) se[d][k] = wredf(se[d][k]);

    __shared__ float sh[4][54];
    int w = tid >> 6;
    if ((tid & 63) == 0) {
        sh[w][0] = at; sh[w][1] = bt; sh[w][2] = ct;
        sh[w][3] = ak; sh[w][4] = bk; sh[w][5] = ckd;
        #pragma unroll
        for (int q = 0; q < 4; q++) {
            sh[w][6 + 2 * q]      = (float)((ck0 >> (16 * q)) & 0xFFFF);
            sh[w][6 + 2 * q + 1]  = (float)((ck1 >> (16 * q)) & 0xFFFF);
            sh[w][14 + 2 * q]     = (float)((ci0 >> (16 * q)) & 0xFFFF);
            sh[w][14 + 2 * q + 1] = (float)((ci1 >> (16 * q)) & 0xFFFF);
        }
        #pragma unroll
        for (int d = 0; d < 4; d++) {
            sh[w][22 + d * 8] = 0.f;
            #pragma unroll
            for (int k = 1; k < 8; k++) sh[w][22 + d * 8 + k] = se[d][k];
        }
    }
    __syncthreads();
    if (tid < 54)
        partM[(size_t)(b * MBLK + blk) * 54 + tid] =
            sh[0][tid] + sh[1][tid] + sh[2][tid] + sh[3][tid];
}

// ---------------- Kernel 5: per-label log-dist sums; folds partM itself ----------------
__global__ __launch_bounds__(256) void k_val_c(const float* __restrict__ maps,
                                               const unsigned long long* __restrict__ ciA,
                                               const float* __restrict__ partM,
                                               float* __restrict__ partV) {
    int b = blockIdx.x / MBLK;
    int blk = blockIdx.x - b * MBLK;
    int tid = threadIdx.x;
    int p0 = (blk * 256 + tid) * 4;
    const float* mb = maps + (size_t)b * 6 * CPB;

    float e0a[4], e1a[4], e2a[4], e3a[4];
    *reinterpret_cast<float4*>(e0a) = *reinterpret_cast<const float4*>(mb + 2 * CPB + p0);
    *reinterpret_cast<float4*>(e1a) = *reinterpret_cast<const float4*>(mb + 3 * CPB + p0);
    *reinterpret_cast<float4*>(e2a) = *reinterpret_cast<const float4*>(mb + 4 * CPB + p0);
    *reinterpret_cast<float4*>(e3a) = *reinterpret_cast<const float4*>(mb + 5 * CPB + p0);
    unsigned long long cia[4];
    *reinterpret_cast<ulonglong2*>(cia)     = *reinterpret_cast<const ulonglong2*>(ciA + b * CPB + p0);
    *reinterpret_cast<ulonglong2*>(cia + 2) = *reinterpret_cast<const ulonglong2*>(ciA + b * CPB + p0 + 2);

    __shared__ float A54[54];
    __shared__ float shm[32];
    __shared__ float shv[8];
    if (tid < 54) {
        float s = 0.f;
        #pragma unroll 5
        for (int j = 0; j < MBLK; j++) s += partM[(size_t)(b * MBLK + j) * 54 + tid];
        A54[tid] = s;
    }
    __syncthreads();
    if (tid < 32) {
        int k = tid & 7;
        shm[tid] = (k == 0) ? 0.f : A54[22 + tid] / fmaxf(A54[6 + k], 1.f);
    }
    if (tid < 8) shv[tid] = (tid != 0 && A54[6 + tid] > 0.f) ? 1.f : 0.f;
    __syncthreads();

    float sv[8];
    #pragma unroll
    for (int k = 0; k < 8; k++) sv[k] = 0.f;
    #pragma unroll
    for (int j = 0; j < 4; j++) {
        unsigned long long ci = cia[j];
        #pragma unroll
        for (int k = 1; k < 8; k++) {
            int c = (int)((ci >> (8 * k)) & 255);
            if (c && shv[k] > 0.5f) {
                float d0 = e0a[j] - shm[k], d1 = e1a[j] - shm[8 + k];
                float d2 = e2a[j] - shm[16 + k], d3 = e3a[j] - shm[24 + k];
                float sq = d0 * d0 + d1 * d1 + d2 * d2 + d3 * d3;
                float dist = sqrtf(fmaxf(sq, 1e-12f));
                float t = fmaxf(dist - 0.5f, 0.f);
                sv[k] += logf(t * t + 1.f) * (float)c;
            }
        }
    }
    #pragma unroll
    for (int k = 1; k < 8; k++) sv[k] = wredf(sv[k]);
    __shared__ float shp[4][8];
    int w = tid >> 6;
    if ((tid & 63) == 0) {
        shp[w][0] = 0.f;
        #pragma unroll
        for (int k = 1; k < 8; k++) shp[w][k] = sv[k];
    }
    __syncthreads();
    if (tid < 8)
        partV[(size_t)(b * MBLK + blk) * 8 + tid] =
            shp[0][tid] + shp[1][tid] + shp[2][tid] + shp[3][tid];
}

// ---------------- Kernel 6: finalize ----------------
__global__ __launch_bounds__(64) void k_final(const float* __restrict__ partM,
                                              const float* __restrict__ partV,
                                              float* __restrict__ out) {
    int tid = threadIdx.x;
    __shared__ float AM[NB][54];
    __shared__ float SV[NB][8];
    __shared__ float tot[NB];
    for (int i = tid; i < NB * 54; i += 64) {
        int b = i / 54, c = i - b * 54;
        float s = 0.f;
        for (int j = 0; j < MBLK; j++) s += partM[(size_t)(b * MBLK + j) * 54 + c];
        AM[b][c] = s;
    }
    {
        int b = tid >> 3, k = tid & 7;
        float s = 0.f;
        for (int j = 0; j < MBLK; j++) s += partV[(size_t)(b * MBLK + j) * 8 + k];
        SV[b][k] = s;
    }
    __syncthreads();
    if (tid < NB) {
        int b = tid;
        const float* A = AM[b];
        float ltext = 1.f - 2.f * A[0] / (A[1] + A[2] + 0.002f);
        float lkern = 1.f - 2.f * A[3] / (A[4] + A[5] + 0.002f);
        float m[4][8];
        float valid[8];
        int nv = 0, ninst = 0;
        #pragma unroll
        for (int k = 0; k < 8; k++) {
            float c = A[6 + k];
            float inv = 1.f / fmaxf(c, 1.f);
            #pragma unroll
            for (int d = 0; d < 4; d++) m[d][k] = (k == 0) ? 0.f : A[22 + d * 8 + k] * inv;
            int pres = (c > 0.f);
            ninst += pres;
            int v = pres && (k != 0);
            nv += v;
            valid[k] = (float)v;
        }
        float s = 0.f;
        for (int i = 1; i < 8; i++) {
            if (valid[i] < 0.5f) continue;
            for (int j = 1; j < 8; j++) {
                if (j == i || valid[j] < 0.5f) continue;
                float sq = 0.f;
                #pragma unroll
                for (int d = 0; d < 4; d++) { float df = m[d][i] - m[d][j]; sq += df * df; }
                float pd = sqrtf(sq > 0.f ? sq : 1.f);
                float t = fmaxf(3.f - pd, 0.f);
                s += logf(t * t + 1.f);
            }
        }
        float pairs = (float)(nv * nv - nv);
        float l_dis = (nv >= 2) ? s / fmaxf(pairs, 1.f) : 0.f;
        float s2 = 0.f;
        for (int k = 0; k < 8; k++) {
            if (A[6 + k] > 0.f) {
                float n2 = 0.f;
                #pragma unroll
                for (int d = 0; d < 4; d++) n2 += m[d][k] * m[d][k];
                s2 += logf(sqrtf(n2) + 1.f);
            }
        }
        float l_reg = s2 / fmaxf((float)ninst, 1.f) * 0.001f;
        float lagg = 0.f;
        #pragma unroll
        for (int k = 0; k < 8; k++)
            lagg += valid[k] * (SV[b][k] / fmaxf(A[14 + k], 1.f));
        lagg /= fmaxf((float)nv, 1.f);
        float le = (nv > 0) ? (lagg + l_dis + l_reg) : 0.f;
        tot[b] = ltext + 0.5f * lkern + 0.25f * le;
    }
    __syncthreads();
    if (tid == 0) {
        float t = 0.f;
        for (int b = 0; b < NB; b++) t += tot[b];
        out[0] = t / (float)NB;
    }
}

extern "C" void kernel_launch(void* const* d_in, const int* in_sizes, int n_in,
                              void* d_out, int out_size, void* d_ws, size_t ws_size,
                              hipStream_t stream) {
    const float* maps        = (const float*)d_in[0];
    const float* gt_texts    = (const float*)d_in[1];
    const float* gt_kernels  = (const float*)d_in[2];
    const int*   gt_instance = (const int*)d_in[3];
    const float* tm          = (const float*)d_in[4];
    char* ws = (char*)d_ws;
    unsigned* cnts  = (unsigned*)(ws + OFF_CNTS);
    unsigned long long* ciA = (unsigned long long*)(ws + OFF_CI);
    unsigned long long* ckA = (unsigned long long*)(ws + OFF_CKC);
    float* partM    = (float*)(ws + OFF_PARTM);
    float* partV    = (float*)(ws + OFF_PARTV);
    int*   posNum   = (int*)(ws + OFF_POSNUM);
    int*   hist0    = (int*)(ws + OFF_HIST0);
    int*   hist1    = (int*)(ws + OFF_HIST1);

    k_pass1<<<NB * PBLK, 256, 0, stream>>>(gt_texts, gt_kernels, gt_instance, tm,
                                           cnts, ciA, ckA, posNum, hist0, hist1);
    k_hist0<<<NB * HSUB, 256, 0, stream>>>(maps, cnts, posNum, hist0);
    k_hist1<<<NB * HSUB, 256, 0, stream>>>(maps, cnts, posNum, hist0, hist1);
    k_main_c<<<NB * MBLK, 256, 0, stream>>>(maps, cnts, ciA, ckA, posNum, hist0, hist1, partM);
    k_val_c<<<NB * MBLK, 256, 0, stream>>>(maps, ciA, partM, partV);
    k_final<<<1, 64, 0, stream>>>(partM, partV, (float*)d_out);
}